// Round 2
// baseline (7580.430 us; speedup 1.0000x reference)
//
#include <hip/hip_runtime.h>
#include <hip/hip_bf16.h>
#include <stdint.h>

// LSTM bidirectional 2-layer, T=512 B=64 D=H=512.
// prep(cast+bias+poison) -> gemm_xg(L0) -> rec(L0) -> gemm_xg(L1) -> poison(d_out) -> rec(L1).
// R4: data-as-flag sync. h history is t-indexed (write-once) and poison-initialized
// (all-ones = NaN encoding; real h is always finite). Consumers spin directly on the
// h data with relaxed agent-scope loads -> ONE L3 trip per step.
// R5: xg is a 268MB read-once stream that was thrashing the 256MB L3 and evicting
// the history lines (R4 counters: FETCH +210MB, WRITE +127MB, step 6.3->8.3us).
// Mark xg stores (gemm epilogue) and xg loads (rec) non-temporal so the history
// (67MB L0 / 134MB L1) stays L3-resident; polls and h-reads become L3 hits.

typedef __attribute__((ext_vector_type(8))) _Float16 half8;
typedef __attribute__((ext_vector_type(4))) float f32x4;
typedef unsigned long long ull;

#define AL(p) __hip_atomic_load((p), __ATOMIC_RELAXED, __HIP_MEMORY_SCOPE_AGENT)
#define AS(p, v) __hip_atomic_store((p), (v), __ATOMIC_RELAXED, __HIP_MEMORY_SCOPE_AGENT)

__device__ __forceinline__ unsigned short f2h(float f) {
    union { _Float16 h; unsigned short u; } c; c.h = (_Float16)f; return c.u;
}
__device__ __forceinline__ float h2f(unsigned short u) {
    union { _Float16 h; unsigned short u; } c; c.u = u; return (float)c.h;
}

// ---------------- prep: casts, bias sums, poison L0 history ----------------
__global__ __launch_bounds__(256) void prep_kernel(
    const float* __restrict__ x,
    const float* __restrict__ w0f, const float* __restrict__ w0b,
    const float* __restrict__ w1f, const float* __restrict__ w1b,
    const float* __restrict__ bi0f, const float* __restrict__ bh0f,
    const float* __restrict__ bi0b, const float* __restrict__ bh0b,
    const float* __restrict__ bi1f, const float* __restrict__ bh1f,
    const float* __restrict__ bi1b, const float* __restrict__ bh1b,
    unsigned short* __restrict__ xh,
    unsigned short* __restrict__ wihh,
    float* __restrict__ bias,
    uint32_t* __restrict__ in1p)           // poison target: in1, 67.1MB
{
    const long total = 9963520L;   // units of 16B quads
    long stride = (long)gridDim.x * blockDim.x;
    for (long i = (long)blockIdx.x * blockDim.x + threadIdx.x; i < total; i += stride) {
        if (i < 4194304L) {                       // x: fp32 -> fp16 (16.78M elems)
            float4 v = ((const float4*)x)[i];
            ushort4 o; o.x=f2h(v.x); o.y=f2h(v.y); o.z=f2h(v.z); o.w=f2h(v.w);
            ((ushort4*)xh)[i] = o;
        } else if (i < 5767168L) {                // w_ih casts: [w0f][w0b][w1f][w1b]
            long j = i - 4194304L;
            const float* src; long sq;
            if (j < 262144L)       { src = w0f; sq = j;            }
            else if (j < 524288L)  { src = w0b; sq = j - 262144L;  }
            else if (j < 1048576L) { src = w1f; sq = j - 524288L;  }
            else                   { src = w1b; sq = j - 1048576L; }
            float4 v = ((const float4*)src)[sq];
            ushort4 o; o.x=f2h(v.x); o.y=f2h(v.y); o.z=f2h(v.z); o.w=f2h(v.w);
            ((ushort4*)wihh)[j] = o;
        } else if (i < 5769216L) {                // bias sums: b_ih + b_hh, 4 x 2048 fp32
            long j = i - 5767168L;                // 0..2047 quads
            int ld = (int)(j >> 9);
            long cq = j & 511L;
            const float* bi = ld==0?bi0f: ld==1?bi0b: ld==2?bi1f:bi1b;
            const float* bh = ld==0?bh0f: ld==1?bh0b: ld==2?bh1f:bh1b;
            float4 a = ((const float4*)bi)[cq];
            float4 b = ((const float4*)bh)[cq];
            float4 o; o.x=a.x+b.x; o.y=a.y+b.y; o.z=a.z+b.z; o.w=a.w+b.w;
            ((float4*)bias)[ld*512 + cq] = o;
        } else {                                  // poison in1 (L0 h-history): all-ones
            long j = i - 5769216L;                // 4,194,304 quads = 67.1MB
            uint4 p; p.x=~0u; p.y=~0u; p.z=~0u; p.w=~0u;
            ((uint4*)in1p)[j] = p;
        }
    }
}

// ---------------- poison kernel: re-poison d_out before rec(L1) ----------------
__global__ __launch_bounds__(256) void poison_kernel(uint4* __restrict__ p, long nq)
{
    long stride = (long)gridDim.x * blockDim.x;
    uint4 v; v.x=~0u; v.y=~0u; v.z=~0u; v.w=~0u;
    for (long i = (long)blockIdx.x * blockDim.x + threadIdx.x; i < nq; i += stride)
        p[i] = v;
}

// ---------------- xg GEMM: xg = A @ W^T, fp16 out, TRANSPOSED layout ----------------
// A: [32768][Din] fp16 row-major (rows = t*64+b). W: [2048][Din] fp16 (B^T layout).
// out[dir]: [t 512][gate 4][hcol 512][brow 64] fp16. Stores are NON-TEMPORAL:
// xg is read exactly once by rec; keep it out of L3 so the h-history stays resident.
__global__ __launch_bounds__(256) void gemm_xg(
    const unsigned short* __restrict__ A,
    const unsigned short* __restrict__ Wf,
    const unsigned short* __restrict__ Wb,
    unsigned short* __restrict__ xg,
    int Din)
{
    __shared__ __align__(16) unsigned short As[4096];   // 128 rows x 32 k, fp16
    __shared__ __align__(16) unsigned short Bs[4096];
    const int dir = blockIdx.z;
    const unsigned short* W = dir ? Wb : Wf;
    unsigned short* out = xg + (size_t)dir * 32768 * 2048;
    const int bn = blockIdx.x, bm = blockIdx.y;
    const int tid = threadIdx.x;
    const int wave = tid >> 6, lane = tid & 63;
    const int q = lane >> 4, ln = lane & 15;
    const int wm = wave >> 1, wn = wave & 1;

    f32x4 acc[4][4];
#pragma unroll
    for (int a = 0; a < 4; ++a)
#pragma unroll
        for (int b = 0; b < 4; ++b) acc[a][b] = (f32x4){0.f, 0.f, 0.f, 0.f};

    const int kiter = Din >> 5;
    for (int kb = 0; kb < kiter; ++kb) {
        __syncthreads();
#pragma unroll
        for (int i = 0; i < 2; ++i) {
            int off = i*4096 + wave*1024 + lane*16;   // byte offset in 8KB tile
            int row = off >> 6;
            int kel = (off & 63) >> 1;
            const unsigned short* sa = A + (size_t)(bm*128 + row)*Din + kb*32 + kel;
            const unsigned short* sb = W + (size_t)(bn*128 + row)*Din + kb*32 + kel;
            __builtin_amdgcn_global_load_lds(
                (const __attribute__((address_space(1))) uint32_t*)sa,
                (__attribute__((address_space(3))) uint32_t*)((char*)As + i*4096 + wave*1024),
                16, 0, 0);
            __builtin_amdgcn_global_load_lds(
                (const __attribute__((address_space(1))) uint32_t*)sb,
                (__attribute__((address_space(3))) uint32_t*)((char*)Bs + i*4096 + wave*1024),
                16, 0, 0);
        }
        __syncthreads();
        half8 af[4], bf[4];
#pragma unroll
        for (int mt = 0; mt < 4; ++mt)
            af[mt] = *(const half8*)((const char*)As + (wm*64 + mt*16 + ln)*64 + q*16);
#pragma unroll
        for (int nt = 0; nt < 4; ++nt)
            bf[nt] = *(const half8*)((const char*)Bs + (wn*64 + nt*16 + ln)*64 + q*16);
#pragma unroll
        for (int mt = 0; mt < 4; ++mt)
#pragma unroll
            for (int nt = 0; nt < 4; ++nt)
                acc[mt][nt] = __builtin_amdgcn_mfma_f32_16x16x32_f16(af[mt], bf[nt], acc[mt][nt], 0, 0, 0);
    }
    // epilogue: transposed store. tile row = t*64 + brow with t = bm*2+wm (128 rows = 2 t).
    const int tt = bm*2 + wm;
#pragma unroll
    for (int mt = 0; mt < 4; ++mt)
#pragma unroll
        for (int nt = 0; nt < 4; ++nt) {
            int col = bn*128 + wn*64 + nt*16 + ln;
            int gate = col >> 9, colg = col & 511;
            union { unsigned short u[4]; ull v; } p;
#pragma unroll
            for (int r = 0; r < 4; ++r) p.u[r] = f2h(acc[mt][nt][r]);
            __builtin_nontemporal_store(p.v,
                (ull*)(out + (((size_t)tt*4 + gate)*512 + colg)*64 + mt*16 + q*4));
        }
}

// ---------------- recurrent kernel: one layer, both directions ----------------
// 256 WGs x 64 threads. WG = (dir, g=hcol/16, bh=batch/16).
// W_hh slice in LDS (64KB, pre-swizzled). h exchange: t-indexed history with
// poison sentinel, relaxed agent-scope loads/stores (sc0/sc1 -> L3). One L3 hop.
// xg loads are NON-TEMPORAL (read-once stream, keep out of L3).
__global__ __launch_bounds__(64) void rec_kernel(
    const unsigned short* __restrict__ xg,    // [dir][t][gate][hcol][brow] fp16, bias-free
    const float* __restrict__ whhf,           // [2048][512] fp32
    const float* __restrict__ whhb,
    const float* __restrict__ bias,           // [2 dir][2048] fp32 (b_ih+b_hh)
    unsigned short* __restrict__ outh,        // layer0: in1 [T][64][1024] fp16 == h history
    float* __restrict__ outf,                 // layer1: d_out fp32 [T][64][1024] == h history
    const int layer)
{
    __shared__ __align__(16) unsigned short whh[32768];  // 64 KB
    __shared__ __align__(16) unsigned short htile[256];  // 512 B repack scratch
    const int bx = blockIdx.x;
    const int dir = bx & 1, g = (bx >> 1) & 31, bh = bx >> 6;
    const int lane = threadIdx.x;
    const int q = lane >> 4, ln = lane & 15;
    const float* whhg = dir ? whhb : whhf;
    const ull POISON = ~0ULL;

    // Preload W_hh rows {gate*512 + g*16 + r}, swizzled so lane's b-frag sits at
    // base(gate,kk) + lane*16 (stride-1, conflict-free ds_read_b128).
    {
        const int kkw = lane >> 2, qqw = lane & 3;
#pragma unroll 4
        for (int Lr = 0; Lr < 64; ++Lr) {
            int gate = Lr >> 4, r16 = Lr & 15;
            const float* src = whhg + (size_t)(gate*512 + g*16 + r16) * 512 + lane*8;
            float4 v0 = *(const float4*)src;
            float4 v1 = *(const float4*)(src + 4);
            union { unsigned short u[8]; half8 v; } p;
            p.u[0]=f2h(v0.x); p.u[1]=f2h(v0.y); p.u[2]=f2h(v0.z); p.u[3]=f2h(v0.w);
            p.u[4]=f2h(v1.x); p.u[5]=f2h(v1.y); p.u[6]=f2h(v1.z); p.u[7]=f2h(v1.w);
            *(half8*)((char*)whh + gate*16384 + kkw*1024 + qqw*256 + r16*16) = p.v;
        }
    }
    __syncthreads();

    const unsigned short* xgd = xg + (size_t)dir * 32768 * 2048;
    const float* biasd = bias + dir * 2048;
    float bv0 = biasd[0*512 + g*16 + ln];
    float bv1 = biasd[1*512 + g*16 + ln];
    float bv2 = biasd[2*512 + g*16 + ln];
    float bv3 = biasd[3*512 + g*16 + ln];

    float carr[4] = {0.f, 0.f, 0.f, 0.f};

#pragma unroll 1
    for (int s = 0; s < 512; ++s) {
        const int t = dir ? (511 - s) : s;

        // xg prefetch: 4 x 8B non-temporal loads; overlaps the h spin.
        ull xv64[4];
#pragma unroll
        for (int nt = 0; nt < 4; ++nt)
            xv64[nt] = __builtin_nontemporal_load(
                (const ull*)(xgd + ((size_t)(t*4 + nt)*512 + g*16 + ln)*64 + bh*16 + q*4));

        f32x4 a0 = {0,0,0,0}, a1 = {0,0,0,0}, a2 = {0,0,0,0}, a3 = {0,0,0,0};

        if (s > 0) {
            const int tp = dir ? (t + 1) : (t - 1);
            if (layer == 0) {
                // fp16 history: 16 chunks x 16B (2 ull each). batch-issue, retry stale.
                const ull* hb = (const ull*)(outh
                    + ((size_t)tp*64 + bh*16 + ln)*1024 + dir*512) + q*2;
                ull hv[32];
#pragma unroll
                for (int kk = 0; kk < 16; ++kk) {
                    hv[2*kk]   = AL(hb + kk*8);
                    hv[2*kk+1] = AL(hb + kk*8 + 1);
                }
                for (int it = 0; it < (1 << 14); ++it) {
                    unsigned stale = 0;
#pragma unroll
                    for (int kk = 0; kk < 16; ++kk)
                        stale |= ((hv[2*kk] == POISON) || (hv[2*kk+1] == POISON)) ? (1u << kk) : 0u;
                    if (!stale) break;
#pragma unroll
                    for (int kk = 0; kk < 16; ++kk)
                        if (stale & (1u << kk)) {
                            hv[2*kk]   = AL(hb + kk*8);
                            hv[2*kk+1] = AL(hb + kk*8 + 1);
                        }
                }
#pragma unroll
                for (int kk = 0; kk < 16; ++kk) {
                    union { ull u[2]; half8 v; } af;
                    af.u[0] = hv[2*kk]; af.u[1] = hv[2*kk+1];
                    const char* wb = (const char*)whh + kk*1024 + lane*16;
                    half8 b0 = *(const half8*)(wb);
                    half8 b1 = *(const half8*)(wb + 16384);
                    half8 b2 = *(const half8*)(wb + 32768);
                    half8 b3 = *(const half8*)(wb + 49152);
                    a0 = __builtin_amdgcn_mfma_f32_16x16x32_f16(af.v, b0, a0, 0, 0, 0);
                    a1 = __builtin_amdgcn_mfma_f32_16x16x32_f16(af.v, b1, a1, 0, 0, 0);
                    a2 = __builtin_amdgcn_mfma_f32_16x16x32_f16(af.v, b2, a2, 0, 0, 0);
                    a3 = __builtin_amdgcn_mfma_f32_16x16x32_f16(af.v, b3, a3, 0, 0, 0);
                }
            } else {
                // fp32 history (the final output buffer): 16 chunks x 32B (4 ull each).
                const ull* hb = (const ull*)(outf
                    + ((size_t)tp*64 + bh*16 + ln)*1024 + dir*512) + q*4;
                ull hv[64];
#pragma unroll
                for (int kk = 0; kk < 16; ++kk) {
                    hv[4*kk]   = AL(hb + kk*16);
                    hv[4*kk+1] = AL(hb + kk*16 + 1);
                    hv[4*kk+2] = AL(hb + kk*16 + 2);
                    hv[4*kk+3] = AL(hb + kk*16 + 3);
                }
                for (int it = 0; it < (1 << 14); ++it) {
                    unsigned stale = 0;
#pragma unroll
                    for (int kk = 0; kk < 16; ++kk)
                        stale |= ((hv[4*kk] == POISON) || (hv[4*kk+1] == POISON) ||
                                  (hv[4*kk+2] == POISON) || (hv[4*kk+3] == POISON)) ? (1u << kk) : 0u;
                    if (!stale) break;
#pragma unroll
                    for (int kk = 0; kk < 16; ++kk)
                        if (stale & (1u << kk)) {
                            hv[4*kk]   = AL(hb + kk*16);
                            hv[4*kk+1] = AL(hb + kk*16 + 1);
                            hv[4*kk+2] = AL(hb + kk*16 + 2);
                            hv[4*kk+3] = AL(hb + kk*16 + 3);
                        }
                }
#pragma unroll
                for (int kk = 0; kk < 16; ++kk) {
                    union { ull u; float f[2]; } c0, c1, c2, c3;
                    c0.u = hv[4*kk]; c1.u = hv[4*kk+1]; c2.u = hv[4*kk+2]; c3.u = hv[4*kk+3];
                    union { unsigned short us[8]; half8 v; } af;
                    af.us[0]=f2h(c0.f[0]); af.us[1]=f2h(c0.f[1]);
                    af.us[2]=f2h(c1.f[0]); af.us[3]=f2h(c1.f[1]);
                    af.us[4]=f2h(c2.f[0]); af.us[5]=f2h(c2.f[1]);
                    af.us[6]=f2h(c3.f[0]); af.us[7]=f2h(c3.f[1]);
                    const char* wb = (const char*)whh + kk*1024 + lane*16;
                    half8 b0 = *(const half8*)(wb);
                    half8 b1 = *(const half8*)(wb + 16384);
                    half8 b2 = *(const half8*)(wb + 32768);
                    half8 b3 = *(const half8*)(wb + 49152);
                    a0 = __builtin_amdgcn_mfma_f32_16x16x32_f16(af.v, b0, a0, 0, 0, 0);
                    a1 = __builtin_amdgcn_mfma_f32_16x16x32_f16(af.v, b1, a1, 0, 0, 0);
                    a2 = __builtin_amdgcn_mfma_f32_16x16x32_f16(af.v, b2, a2, 0, 0, 0);
                    a3 = __builtin_amdgcn_mfma_f32_16x16x32_f16(af.v, b3, a3, 0, 0, 0);
                }
            }
        }

        unsigned short hs[4];
#pragma unroll
        for (int r = 0; r < 4; ++r) {
            float gi = a0[r] + h2f((unsigned short)(xv64[0] >> (16*r))) + bv0;
            float gf = a1[r] + h2f((unsigned short)(xv64[1] >> (16*r))) + bv1;
            float gg = a2[r] + h2f((unsigned short)(xv64[2] >> (16*r))) + bv2;
            float go = a3[r] + h2f((unsigned short)(xv64[3] >> (16*r))) + bv3;
            float si = 1.f / (1.f + __expf(-gi));
            float sf = 1.f / (1.f + __expf(-gf));
            float so = 1.f / (1.f + __expf(-go));
            float tg = 2.f / (1.f + __expf(-2.f*gg)) - 1.f;
            float c  = sf * carr[r] + si * tg;
            carr[r] = c;
            float th = 2.f / (1.f + __expf(-2.f*c)) - 1.f;
            hs[r] = f2h(so * th);
        }

        // repack 16x16 tile via LDS so each lane holds 8B contiguous (row, 4 cols)
#pragma unroll
        for (int r = 0; r < 4; ++r) htile[(q*4 + r)*16 + ln] = hs[r];
        __syncthreads();
        ull hv64 = *(const ull*)(htile + (lane >> 2)*16 + (lane & 3)*4);
        const int row  = bh*16 + (lane >> 2);
        const int colw = g*16 + (lane & 3)*4;

        // single store = history update AND layer output. agent-scope -> L3-visible.
        if (layer == 0) {
            AS((ull*)(outh + ((size_t)t*64 + row)*1024 + dir*512 + colw), hv64);
        } else {
            union { ull u; unsigned short us[4]; } pu; pu.u = hv64;
            union { ull u; float f[2]; } o0, o1;
            o0.f[0] = h2f(pu.us[0]); o0.f[1] = h2f(pu.us[1]);
            o1.f[0] = h2f(pu.us[2]); o1.f[1] = h2f(pu.us[3]);
            ull* dst = (ull*)(outf + ((size_t)t*64 + row)*1024 + dir*512 + colw);
            AS(dst, o0.u);
            AS(dst + 1, o1.u);
        }
        __syncthreads();   // htile reuse guard
    }
}

extern "C" void kernel_launch(void* const* d_in, const int* in_sizes, int n_in,
                              void* d_out, int out_size, void* d_ws, size_t ws_size,
                              hipStream_t stream)
{
    (void)in_sizes; (void)n_in; (void)out_size; (void)ws_size;
    const float* x       = (const float*)d_in[0];
    const float* w_ih0_f = (const float*)d_in[1];
    const float* w_hh0_f = (const float*)d_in[2];
    const float* b_ih0_f = (const float*)d_in[3];
    const float* b_hh0_f = (const float*)d_in[4];
    const float* w_ih0_b = (const float*)d_in[5];
    const float* w_hh0_b = (const float*)d_in[6];
    const float* b_ih0_b = (const float*)d_in[7];
    const float* b_hh0_b = (const float*)d_in[8];
    const float* w_ih1_f = (const float*)d_in[9];
    const float* w_hh1_f = (const float*)d_in[10];
    const float* b_ih1_f = (const float*)d_in[11];
    const float* b_hh1_f = (const float*)d_in[12];
    const float* w_ih1_b = (const float*)d_in[13];
    const float* w_hh1_b = (const float*)d_in[14];
    const float* b_ih1_b = (const float*)d_in[15];
    const float* b_hh1_b = (const float*)d_in[16];

    // workspace layout (bytes): xg 256MB | wih_h 12MB | bias 32KB
    char* ws = (char*)d_ws;
    unsigned short* xg    = (unsigned short*)(ws + 0);
    unsigned short* wihh  = (unsigned short*)(ws + 268435456L);
    float*          bias  = (float*)         (ws + 281018368L);

    // scratch stashed inside d_out (consumed before final output is written):
    unsigned short* in1 = (unsigned short*)d_out;                      // 67MB fp16 [T][64][1024]
    unsigned short* xh  = (unsigned short*)((char*)d_out + 67108864L); // 33.5MB fp16 x
    float* outf = (float*)d_out;

    prep_kernel<<<dim3(1024), dim3(256), 0, stream>>>(
        x, w_ih0_f, w_ih0_b, w_ih1_f, w_ih1_b,
        b_ih0_f, b_hh0_f, b_ih0_b, b_hh0_b,
        b_ih1_f, b_hh1_f, b_ih1_b, b_hh1_b,
        xh, wihh, bias, (uint32_t*)in1);

    // layer 0: history buffer == in1 (poisoned by prep)
    gemm_xg<<<dim3(16, 256, 2), dim3(256), 0, stream>>>(
        xh, wihh, wihh + 1048576, xg, 512);
    rec_kernel<<<dim3(256), dim3(64), 0, stream>>>(
        xg, w_hh0_f, w_hh0_b, bias, in1, (float*)nullptr, 0);

    // layer 1: history buffer == final fp32 output (re-poisoned after gemm consumed in1)
    gemm_xg<<<dim3(16, 256, 2), dim3(256), 0, stream>>>(
        in1, wihh + 2097152, wihh + 4194304, xg, 1024);
    poison_kernel<<<dim3(2048), dim3(256), 0, stream>>>(
        (uint4*)d_out, 8388608L);
    rec_kernel<<<dim3(256), dim3(64), 0, stream>>>(
        xg, w_hh1_f, w_hh1_b, bias + 4096, (unsigned short*)nullptr, outf, 1);
}

// Round 4
// 6215.300 us; speedup vs baseline: 1.2196x; 1.2196x over previous
//
#include <hip/hip_runtime.h>
#include <hip/hip_bf16.h>
#include <stdint.h>

// LSTM bidirectional 2-layer, T=512 B=64 D=H=512.
// prep(cast+bias+ring-init) -> gemm_xg(L0) -> rec(L0) -> gemm_xg(L1) -> rec(L1).
// R6/R7: single-hop sync on a COMPACT 512KB ring with tag-in-data.
//   h = sigma*tanh in [-1,1] => fp16 bit14 is ALWAYS 0 (biased exp <= 15).
//   Each 8B chunk (4 fp16) has 4 free tag bits (bit14 of each half). Producer
//   stores h with a tag pattern via one relaxed agent-scope 8B atomic (no
//   vmcnt ack, no flag, no fence). Consumer's h-load IS the poll: retry chunks
//   whose tag pattern != expected.
// R7 fix (R6 was racy at layer/replay boundaries): ORTHOGONAL tag alphabets.
//   L0 parity0/1 -> 0000 / 1111;  L1 parity0/1 -> 1010 / 0101 (half-index bits).
//   Ring init (prep, every launch) = neutral 0011. L0 residue never matches an
//   L1 expectation, init matches nothing, replay residue is re-initialized.
//   Within a layer: slot holds only init / s-1 (match) / s-5 (opposite parity,
//   no match) given producer-consumer skew <= 1 step. No false match possible.
// R5 carry-over: xg stores/loads non-temporal (268MB read-once stream stays
// out of L3 so the ring stays hot).

typedef __attribute__((ext_vector_type(8))) _Float16 half8;
typedef __attribute__((ext_vector_type(4))) float f32x4;
typedef unsigned long long ull;

#define AL(p) __hip_atomic_load((p), __ATOMIC_RELAXED, __HIP_MEMORY_SCOPE_AGENT)
#define AS(p, v) __hip_atomic_store((p), (v), __ATOMIC_RELAXED, __HIP_MEMORY_SCOPE_AGENT)

#define TAGMASK 0x4000400040004000ULL   // bit14 of halves 0..3
#define PAT_L1A 0x0000400000004000ULL   // halves 0,2  (L1 parity 0)
#define PAT_L1B 0x4000000040000000ULL   // halves 1,3  (L1 parity 1)
// neutral ring-init pattern: halves 0,1 -> matches no expectation of any layer
#define PAT_INIT_LO 0x40004000u
#define PAT_INIT_HI 0x00000000u

__device__ __forceinline__ unsigned short f2h(float f) {
    union { _Float16 h; unsigned short u; } c; c.h = (_Float16)f; return c.u;
}
__device__ __forceinline__ float h2f(unsigned short u) {
    union { _Float16 h; unsigned short u; } c; c.u = u; return (float)c.h;
}

// ---------------- prep: casts, bias sums, ring init (neutral pattern) ----------------
__global__ __launch_bounds__(256) void prep_kernel(
    const float* __restrict__ x,
    const float* __restrict__ w0f, const float* __restrict__ w0b,
    const float* __restrict__ w1f, const float* __restrict__ w1b,
    const float* __restrict__ bi0f, const float* __restrict__ bh0f,
    const float* __restrict__ bi0b, const float* __restrict__ bh0b,
    const float* __restrict__ bi1f, const float* __restrict__ bh1f,
    const float* __restrict__ bi1b, const float* __restrict__ bh1b,
    unsigned short* __restrict__ xh,
    unsigned short* __restrict__ wihh,
    float* __restrict__ bias,
    uint32_t* __restrict__ hbufi)          // ring init: 512KB neutral pattern
{
    const long total = 5801984L;   // units of 16B quads
    long stride = (long)gridDim.x * blockDim.x;
    for (long i = (long)blockIdx.x * blockDim.x + threadIdx.x; i < total; i += stride) {
        if (i < 4194304L) {                       // x: fp32 -> fp16 (16.78M elems)
            float4 v = ((const float4*)x)[i];
            ushort4 o; o.x=f2h(v.x); o.y=f2h(v.y); o.z=f2h(v.z); o.w=f2h(v.w);
            ((ushort4*)xh)[i] = o;
        } else if (i < 5767168L) {                // w_ih casts: [w0f][w0b][w1f][w1b]
            long j = i - 4194304L;
            const float* src; long sq;
            if (j < 262144L)       { src = w0f; sq = j;            }
            else if (j < 524288L)  { src = w0b; sq = j - 262144L;  }
            else if (j < 1048576L) { src = w1f; sq = j - 524288L;  }
            else                   { src = w1b; sq = j - 1048576L; }
            float4 v = ((const float4*)src)[sq];
            ushort4 o; o.x=f2h(v.x); o.y=f2h(v.y); o.z=f2h(v.z); o.w=f2h(v.w);
            ((ushort4*)wihh)[j] = o;
        } else if (i < 5769216L) {                // bias sums: b_ih + b_hh, 4 x 2048 fp32
            long j = i - 5767168L;                // 0..2047 quads
            int ld = (int)(j >> 9);
            long cq = j & 511L;
            const float* bi = ld==0?bi0f: ld==1?bi0b: ld==2?bi1f:bi1b;
            const float* bh = ld==0?bh0f: ld==1?bh0b: ld==2?bh1f:bh1b;
            float4 a = ((const float4*)bi)[cq];
            float4 b = ((const float4*)bh)[cq];
            float4 o; o.x=a.x+b.x; o.y=a.y+b.y; o.z=a.z+b.z; o.w=a.w+b.w;
            ((float4*)bias)[ld*512 + cq] = o;
        } else {                                  // ring init: 32768 quads = 512KB
            long j = i - 5769216L;
            uint4 p; p.x=PAT_INIT_LO; p.y=PAT_INIT_HI; p.z=PAT_INIT_LO; p.w=PAT_INIT_HI;
            ((uint4*)hbufi)[j] = p;
        }
    }
}

// ---------------- xg GEMM: xg = A @ W^T, fp16 out, TRANSPOSED layout ----------------
// A: [32768][Din] fp16 row-major (rows = t*64+b). W: [2048][Din] fp16 (B^T layout).
// out[dir]: [t 512][gate 4][hcol 512][brow 64] fp16. Stores NON-TEMPORAL
// (read exactly once by rec; keep the stream out of L3 so the ring stays hot).
__global__ __launch_bounds__(256) void gemm_xg(
    const unsigned short* __restrict__ A,
    const unsigned short* __restrict__ Wf,
    const unsigned short* __restrict__ Wb,
    unsigned short* __restrict__ xg,
    int Din)
{
    __shared__ __align__(16) unsigned short As[4096];   // 128 rows x 32 k, fp16
    __shared__ __align__(16) unsigned short Bs[4096];
    const int dir = blockIdx.z;
    const unsigned short* W = dir ? Wb : Wf;
    unsigned short* out = xg + (size_t)dir * 32768 * 2048;
    const int bn = blockIdx.x, bm = blockIdx.y;
    const int tid = threadIdx.x;
    const int wave = tid >> 6, lane = tid & 63;
    const int q = lane >> 4, ln = lane & 15;
    const int wm = wave >> 1, wn = wave & 1;

    f32x4 acc[4][4];
#pragma unroll
    for (int a = 0; a < 4; ++a)
#pragma unroll
        for (int b = 0; b < 4; ++b) acc[a][b] = (f32x4){0.f, 0.f, 0.f, 0.f};

    const int kiter = Din >> 5;
    for (int kb = 0; kb < kiter; ++kb) {
        __syncthreads();
#pragma unroll
        for (int i = 0; i < 2; ++i) {
            int off = i*4096 + wave*1024 + lane*16;   // byte offset in 8KB tile
            int row = off >> 6;
            int kel = (off & 63) >> 1;
            const unsigned short* sa = A + (size_t)(bm*128 + row)*Din + kb*32 + kel;
            const unsigned short* sb = W + (size_t)(bn*128 + row)*Din + kb*32 + kel;
            __builtin_amdgcn_global_load_lds(
                (const __attribute__((address_space(1))) uint32_t*)sa,
                (__attribute__((address_space(3))) uint32_t*)((char*)As + i*4096 + wave*1024),
                16, 0, 0);
            __builtin_amdgcn_global_load_lds(
                (const __attribute__((address_space(1))) uint32_t*)sb,
                (__attribute__((address_space(3))) uint32_t*)((char*)Bs + i*4096 + wave*1024),
                16, 0, 0);
        }
        __syncthreads();
        half8 af[4], bf[4];
#pragma unroll
        for (int mt = 0; mt < 4; ++mt)
            af[mt] = *(const half8*)((const char*)As + (wm*64 + mt*16 + ln)*64 + q*16);
#pragma unroll
        for (int nt = 0; nt < 4; ++nt)
            bf[nt] = *(const half8*)((const char*)Bs + (wn*64 + nt*16 + ln)*64 + q*16);
#pragma unroll
        for (int mt = 0; mt < 4; ++mt)
#pragma unroll
            for (int nt = 0; nt < 4; ++nt)
                acc[mt][nt] = __builtin_amdgcn_mfma_f32_16x16x32_f16(af[mt], bf[nt], acc[mt][nt], 0, 0, 0);
    }
    // epilogue: transposed store. tile row = t*64 + brow with t = bm*2+wm (128 rows = 2 t).
    const int tt = bm*2 + wm;
#pragma unroll
    for (int mt = 0; mt < 4; ++mt)
#pragma unroll
        for (int nt = 0; nt < 4; ++nt) {
            int col = bn*128 + wn*64 + nt*16 + ln;
            int gate = col >> 9, colg = col & 511;
            union { unsigned short u[4]; ull v; } p;
#pragma unroll
            for (int r = 0; r < 4; ++r) p.u[r] = f2h(acc[mt][nt][r]);
            __builtin_nontemporal_store(p.v,
                (ull*)(out + (((size_t)tt*4 + gate)*512 + colg)*64 + mt*16 + q*4));
        }
}

// ---------------- recurrent kernel: one layer, both directions ----------------
// 256 WGs x 64 threads. WG = (dir, g=hcol/16, bh=batch/16).
// W_hh slice in LDS (64KB, pre-swizzled). h exchange: 4-slot tagged ring,
// relaxed agent atomics. Load IS the poll (per-layer tag alphabet). One L3 hop.
__global__ __launch_bounds__(64) void rec_kernel(
    const unsigned short* __restrict__ xg,    // [dir][t][gate][hcol][brow] fp16, bias-free
    const float* __restrict__ whhf,           // [2048][512] fp32
    const float* __restrict__ whhb,
    const float* __restrict__ bias,           // [2 dir][2048] fp32 (b_ih+b_hh)
    unsigned short* __restrict__ hbuf,        // ring [4 slot][2 dir][64][512] fp16, tagged
    unsigned short* __restrict__ outh,        // layer0: in1 [T][64][1024] fp16
    float* __restrict__ outf,                 // layer1: d_out fp32 [T][64][1024]
    const int layer)
{
    __shared__ __align__(16) unsigned short whh[32768];  // 64 KB
    __shared__ __align__(16) unsigned short htile[256];  // 512 B repack scratch
    const int bx = blockIdx.x;
    const int dir = bx & 1, g = (bx >> 1) & 31, bh = bx >> 6;
    const int lane = threadIdx.x;
    const int q = lane >> 4, ln = lane & 15;
    const float* whhg = dir ? whhb : whhf;
    // per-layer orthogonal tag alphabet (parity 0 / parity 1)
    const ull pat0 = layer ? PAT_L1A : 0ULL;
    const ull pat1 = layer ? PAT_L1B : TAGMASK;

    // Preload W_hh rows {gate*512 + g*16 + r}, swizzled so lane's b-frag sits at
    // base(gate,kk) + lane*16 (stride-1, conflict-free ds_read_b128).
    {
        const int kkw = lane >> 2, qqw = lane & 3;
#pragma unroll 4
        for (int Lr = 0; Lr < 64; ++Lr) {
            int gate = Lr >> 4, r16 = Lr & 15;
            const float* src = whhg + (size_t)(gate*512 + g*16 + r16) * 512 + lane*8;
            float4 v0 = *(const float4*)src;
            float4 v1 = *(const float4*)(src + 4);
            union { unsigned short u[8]; half8 v; } p;
            p.u[0]=f2h(v0.x); p.u[1]=f2h(v0.y); p.u[2]=f2h(v0.z); p.u[3]=f2h(v0.w);
            p.u[4]=f2h(v1.x); p.u[5]=f2h(v1.y); p.u[6]=f2h(v1.z); p.u[7]=f2h(v1.w);
            *(half8*)((char*)whh + gate*16384 + kkw*1024 + qqw*256 + r16*16) = p.v;
        }
    }
    __syncthreads();

    const unsigned short* xgd = xg + (size_t)dir * 32768 * 2048;
    const float* biasd = bias + dir * 2048;
    float bv0 = biasd[0*512 + g*16 + ln];
    float bv1 = biasd[1*512 + g*16 + ln];
    float bv2 = biasd[2*512 + g*16 + ln];
    float bv3 = biasd[3*512 + g*16 + ln];

    float carr[4] = {0.f, 0.f, 0.f, 0.f};

#pragma unroll 1
    for (int s = 0; s < 512; ++s) {
        const int t = dir ? (511 - s) : s;

        // xg prefetch: 4 x 8B non-temporal loads; overlaps the h poll.
        ull xv64[4];
#pragma unroll
        for (int nt = 0; nt < 4; ++nt)
            xv64[nt] = __builtin_nontemporal_load(
                (const ull*)(xgd + ((size_t)(t*4 + nt)*512 + g*16 + ln)*64 + bh*16 + q*4));

        f32x4 a0 = {0,0,0,0}, a1 = {0,0,0,0}, a2 = {0,0,0,0}, a3 = {0,0,0,0};

        if (s > 0) {
            const int slot_r = (s - 1) & 3;
            const ull epat = (((s - 1) >> 2) & 1) ? pat1 : pat0;
            const ull* hb = (const ull*)(hbuf
                + ((size_t)(slot_r*2 + dir)*64 + bh*16 + ln)*512) + q*2;
            // 32 x 8B tagged chunks: batch-issue, retry only stale (load IS poll).
            ull hv[32];
#pragma unroll
            for (int kk = 0; kk < 16; ++kk) {
                hv[2*kk]   = AL(hb + kk*8);
                hv[2*kk+1] = AL(hb + kk*8 + 1);
            }
            for (int it = 0; it < (1 << 13); ++it) {
                unsigned stale = 0;
#pragma unroll
                for (int c = 0; c < 32; ++c)
                    stale |= ((hv[c] & TAGMASK) != epat) ? (1u << c) : 0u;
                if (!stale) break;
#pragma unroll
                for (int c = 0; c < 32; ++c)
                    if (stale & (1u << c))
                        hv[c] = AL(hb + (c >> 1)*8 + (c & 1));
            }
#pragma unroll
            for (int kk = 0; kk < 16; ++kk) {
                union { ull u[2]; half8 v; } af;
                af.u[0] = hv[2*kk]   & ~TAGMASK;
                af.u[1] = hv[2*kk+1] & ~TAGMASK;
                const char* wb = (const char*)whh + kk*1024 + lane*16;
                half8 b0 = *(const half8*)(wb);
                half8 b1 = *(const half8*)(wb + 16384);
                half8 b2 = *(const half8*)(wb + 32768);
                half8 b3 = *(const half8*)(wb + 49152);
                a0 = __builtin_amdgcn_mfma_f32_16x16x32_f16(af.v, b0, a0, 0, 0, 0);
                a1 = __builtin_amdgcn_mfma_f32_16x16x32_f16(af.v, b1, a1, 0, 0, 0);
                a2 = __builtin_amdgcn_mfma_f32_16x16x32_f16(af.v, b2, a2, 0, 0, 0);
                a3 = __builtin_amdgcn_mfma_f32_16x16x32_f16(af.v, b3, a3, 0, 0, 0);
            }
        }

        unsigned short hs[4];
#pragma unroll
        for (int r = 0; r < 4; ++r) {
            float gi = a0[r] + h2f((unsigned short)(xv64[0] >> (16*r))) + bv0;
            float gf = a1[r] + h2f((unsigned short)(xv64[1] >> (16*r))) + bv1;
            float gg = a2[r] + h2f((unsigned short)(xv64[2] >> (16*r))) + bv2;
            float go = a3[r] + h2f((unsigned short)(xv64[3] >> (16*r))) + bv3;
            float si = 1.f / (1.f + __expf(-gi));
            float sf = 1.f / (1.f + __expf(-gf));
            float so = 1.f / (1.f + __expf(-go));
            float tg = 2.f / (1.f + __expf(-2.f*gg)) - 1.f;
            float c  = sf * carr[r] + si * tg;
            carr[r] = c;
            float th = 2.f / (1.f + __expf(-2.f*c)) - 1.f;
            hs[r] = f2h(so * th);
        }

        // repack 16x16 tile via LDS so each lane holds 8B contiguous (row, 4 cols)
#pragma unroll
        for (int r = 0; r < 4; ++r) htile[(q*4 + r)*16 + ln] = hs[r];
        __syncthreads();
        ull hv64 = *(const ull*)(htile + (lane >> 2)*16 + (lane & 3)*4);
        const int row  = bh*16 + (lane >> 2);
        const int colw = g*16 + (lane & 3)*4;

        // ring store FIRST (critical path): tagged, single 8B relaxed atomic.
        // h in [-1,1] => tag bits of hv64 are naturally 0; OR in this parity's pattern.
        const int slot_w = s & 3;
        const ull wpat = ((s >> 2) & 1) ? pat1 : pat0;
        AS((ull*)(hbuf + ((size_t)(slot_w*2 + dir)*64 + row)*512 + colw), hv64 | wpat);

        // layer output: plain non-temporal store, off the critical path.
        if (layer == 0) {
            __builtin_nontemporal_store(hv64,
                (ull*)(outh + ((size_t)t*64 + row)*1024 + dir*512 + colw));
        } else {
            union { ull u; unsigned short us[4]; } pu; pu.u = hv64;
            union { ull u; float f[2]; } o0, o1;
            o0.f[0] = h2f(pu.us[0]); o0.f[1] = h2f(pu.us[1]);
            o1.f[0] = h2f(pu.us[2]); o1.f[1] = h2f(pu.us[3]);
            ull* dst = (ull*)(outf + ((size_t)t*64 + row)*1024 + dir*512 + colw);
            __builtin_nontemporal_store(o0.u, dst);
            __builtin_nontemporal_store(o1.u, dst + 1);
        }
        __syncthreads();   // htile reuse guard
    }
}

extern "C" void kernel_launch(void* const* d_in, const int* in_sizes, int n_in,
                              void* d_out, int out_size, void* d_ws, size_t ws_size,
                              hipStream_t stream)
{
    (void)in_sizes; (void)n_in; (void)out_size; (void)ws_size;
    const float* x       = (const float*)d_in[0];
    const float* w_ih0_f = (const float*)d_in[1];
    const float* w_hh0_f = (const float*)d_in[2];
    const float* b_ih0_f = (const float*)d_in[3];
    const float* b_hh0_f = (const float*)d_in[4];
    const float* w_ih0_b = (const float*)d_in[5];
    const float* w_hh0_b = (const float*)d_in[6];
    const float* b_ih0_b = (const float*)d_in[7];
    const float* b_hh0_b = (const float*)d_in[8];
    const float* w_ih1_f = (const float*)d_in[9];
    const float* w_hh1_f = (const float*)d_in[10];
    const float* b_ih1_f = (const float*)d_in[11];
    const float* b_hh1_f = (const float*)d_in[12];
    const float* w_ih1_b = (const float*)d_in[13];
    const float* w_hh1_b = (const float*)d_in[14];
    const float* b_ih1_b = (const float*)d_in[15];
    const float* b_hh1_b = (const float*)d_in[16];

    // workspace layout (bytes): xg 256MB | wih_h 12MB | bias 32KB | hbuf ring 512KB
    char* ws = (char*)d_ws;
    unsigned short* xg    = (unsigned short*)(ws + 0);
    unsigned short* wihh  = (unsigned short*)(ws + 268435456L);
    float*          bias  = (float*)         (ws + 281018368L);
    unsigned short* hbuf  = (unsigned short*)(ws + 281051136L);

    // scratch stashed inside d_out (consumed before final output is written):
    unsigned short* in1 = (unsigned short*)d_out;                      // 67MB fp16 [T][64][1024]
    unsigned short* xh  = (unsigned short*)((char*)d_out + 67108864L); // 33.5MB fp16 x
    float* outf = (float*)d_out;

    prep_kernel<<<dim3(1024), dim3(256), 0, stream>>>(
        x, w_ih0_f, w_ih0_b, w_ih1_f, w_ih1_b,
        b_ih0_f, b_hh0_f, b_ih0_b, b_hh0_b,
        b_ih1_f, b_hh1_f, b_ih1_b, b_hh1_b,
        xh, wihh, bias, (uint32_t*)hbuf);

    // layer 0 (tag alphabet {0000,1111})
    gemm_xg<<<dim3(16, 256, 2), dim3(256), 0, stream>>>(
        xh, wihh, wihh + 1048576, xg, 512);
    rec_kernel<<<dim3(256), dim3(64), 0, stream>>>(
        xg, w_hh0_f, w_hh0_b, bias, hbuf, in1, (float*)nullptr, 0);

    // layer 1 (tag alphabet {1010,0101} — orthogonal to L0 residue and to init)
    gemm_xg<<<dim3(16, 256, 2), dim3(256), 0, stream>>>(
        in1, wihh + 2097152, wihh + 4194304, xg, 1024);
    rec_kernel<<<dim3(256), dim3(64), 0, stream>>>(
        xg, w_hh1_f, w_hh1_b, bias + 4096, hbuf,
        (unsigned short*)nullptr, outf, 1);
}

// Round 5
// 5589.433 us; speedup vs baseline: 1.3562x; 1.1120x over previous
//
#include <hip/hip_runtime.h>
#include <hip/hip_bf16.h>
#include <stdint.h>

// LSTM bidirectional 2-layer, T=512 B=64 D=H=512.
// prep(cast+bias+ring-init) -> gemm_xg(L0) -> rec(L0) -> gemm_xg(L1) -> rec(L1).
// R7: single-hop sync on a COMPACT 512KB ring with per-u16 tag-in-data
//   (h in [-1,1] => fp16 bit14 always 0). Orthogonal per-layer tag alphabets:
//   L0 {0000,1111}, L1 {1010,0101}, ring init = neutral 0011 (matches nothing).
// R8: fat-WG consumer to kill L3 request congestion (R7: per-step 5.3us of
//   which ~4.8us stall; 524k coherent 8B poll requests/step from 256 narrow WGs).
//   - 128 WGs x 512 thr (8 waves = 4 gates x 2 col-halves), WG = (dir,bh,32 cols).
//   - W_hh slice in REGISTERS (16 half8/lane, preloaded once). No LDS weights.
//   - h tile (16 rows x 512) loaded ONCE per WG: 2x16B sc0/sc1 loads per lane
//     (per-u16 tags make 16B-across-8B-atomics tearing safe), tag-checked,
//     stripped, staged into XOR-swizzled LDS; MFMA A-frags read conflict-free.
//   - gate regroup via 8KB LDS accbuf; 2 waves do pointwise+ring store while
//     6 waves proceed to next poll.
// R5 carry-over: xg stores/loads non-temporal (268MB read-once stream).

typedef __attribute__((ext_vector_type(8))) _Float16 half8;
typedef __attribute__((ext_vector_type(4))) float f32x4;
typedef __attribute__((ext_vector_type(4))) uint32_t u32x4;
typedef unsigned long long ull;

#define AS(p, v) __hip_atomic_store((p), (v), __ATOMIC_RELAXED, __HIP_MEMORY_SCOPE_AGENT)

#define TAGMASK 0x4000400040004000ULL   // bit14 of halves 0..3
#define TM32    0x40004000u
#define PAT_L1A 0x0000400000004000ULL   // halves 0,2  (L1 parity 0)
#define PAT_L1B 0x4000000040000000ULL   // halves 1,3  (L1 parity 1)
// neutral ring-init pattern: halves 0,1 -> per-16B dwords alternate full/zero
// tag; matches no layer's expectation (which needs ALL dwords consistent).
#define PAT_INIT_LO 0x40004000u
#define PAT_INIT_HI 0x00000000u

__device__ __forceinline__ unsigned short f2h(float f) {
    union { _Float16 h; unsigned short u; } c; c.h = (_Float16)f; return c.u;
}
__device__ __forceinline__ float h2f(unsigned short u) {
    union { _Float16 h; unsigned short u; } c; c.u = u; return (float)c.h;
}

// ---------------- prep: casts, bias sums, ring init (neutral pattern) ----------------
__global__ __launch_bounds__(256) void prep_kernel(
    const float* __restrict__ x,
    const float* __restrict__ w0f, const float* __restrict__ w0b,
    const float* __restrict__ w1f, const float* __restrict__ w1b,
    const float* __restrict__ bi0f, const float* __restrict__ bh0f,
    const float* __restrict__ bi0b, const float* __restrict__ bh0b,
    const float* __restrict__ bi1f, const float* __restrict__ bh1f,
    const float* __restrict__ bi1b, const float* __restrict__ bh1b,
    unsigned short* __restrict__ xh,
    unsigned short* __restrict__ wihh,
    float* __restrict__ bias,
    uint32_t* __restrict__ hbufi)          // ring init: 512KB neutral pattern
{
    const long total = 5801984L;   // units of 16B quads
    long stride = (long)gridDim.x * blockDim.x;
    for (long i = (long)blockIdx.x * blockDim.x + threadIdx.x; i < total; i += stride) {
        if (i < 4194304L) {                       // x: fp32 -> fp16 (16.78M elems)
            float4 v = ((const float4*)x)[i];
            ushort4 o; o.x=f2h(v.x); o.y=f2h(v.y); o.z=f2h(v.z); o.w=f2h(v.w);
            ((ushort4*)xh)[i] = o;
        } else if (i < 5767168L) {                // w_ih casts: [w0f][w0b][w1f][w1b]
            long j = i - 4194304L;
            const float* src; long sq;
            if (j < 262144L)       { src = w0f; sq = j;            }
            else if (j < 524288L)  { src = w0b; sq = j - 262144L;  }
            else if (j < 1048576L) { src = w1f; sq = j - 524288L;  }
            else                   { src = w1b; sq = j - 1048576L; }
            float4 v = ((const float4*)src)[sq];
            ushort4 o; o.x=f2h(v.x); o.y=f2h(v.y); o.z=f2h(v.z); o.w=f2h(v.w);
            ((ushort4*)wihh)[j] = o;
        } else if (i < 5769216L) {                // bias sums: b_ih + b_hh, 4 x 2048 fp32
            long j = i - 5767168L;                // 0..2047 quads
            int ld = (int)(j >> 9);
            long cq = j & 511L;
            const float* bi = ld==0?bi0f: ld==1?bi0b: ld==2?bi1f:bi1b;
            const float* bh = ld==0?bh0f: ld==1?bh0b: ld==2?bh1f:bh1b;
            float4 a = ((const float4*)bi)[cq];
            float4 b = ((const float4*)bh)[cq];
            float4 o; o.x=a.x+b.x; o.y=a.y+b.y; o.z=a.z+b.z; o.w=a.w+b.w;
            ((float4*)bias)[ld*512 + cq] = o;
        } else {                                  // ring init: 32768 quads = 512KB
            long j = i - 5769216L;
            uint4 p; p.x=PAT_INIT_LO; p.y=PAT_INIT_HI; p.z=PAT_INIT_LO; p.w=PAT_INIT_HI;
            ((uint4*)hbufi)[j] = p;
        }
    }
}

// ---------------- xg GEMM: xg = A @ W^T, fp16 out, TRANSPOSED layout ----------------
// A: [32768][Din] fp16 row-major (rows = t*64+b). W: [2048][Din] fp16 (B^T layout).
// out[dir]: [t 512][gate 4][hcol 512][brow 64] fp16. Stores NON-TEMPORAL
// (read exactly once by rec; keep the stream out of L3 so the ring stays hot).
__global__ __launch_bounds__(256) void gemm_xg(
    const unsigned short* __restrict__ A,
    const unsigned short* __restrict__ Wf,
    const unsigned short* __restrict__ Wb,
    unsigned short* __restrict__ xg,
    int Din)
{
    __shared__ __align__(16) unsigned short As[4096];   // 128 rows x 32 k, fp16
    __shared__ __align__(16) unsigned short Bs[4096];
    const int dir = blockIdx.z;
    const unsigned short* W = dir ? Wb : Wf;
    unsigned short* out = xg + (size_t)dir * 32768 * 2048;
    const int bn = blockIdx.x, bm = blockIdx.y;
    const int tid = threadIdx.x;
    const int wave = tid >> 6, lane = tid & 63;
    const int q = lane >> 4, ln = lane & 15;
    const int wm = wave >> 1, wn = wave & 1;

    f32x4 acc[4][4];
#pragma unroll
    for (int a = 0; a < 4; ++a)
#pragma unroll
        for (int b = 0; b < 4; ++b) acc[a][b] = (f32x4){0.f, 0.f, 0.f, 0.f};

    const int kiter = Din >> 5;
    for (int kb = 0; kb < kiter; ++kb) {
        __syncthreads();
#pragma unroll
        for (int i = 0; i < 2; ++i) {
            int off = i*4096 + wave*1024 + lane*16;   // byte offset in 8KB tile
            int row = off >> 6;
            int kel = (off & 63) >> 1;
            const unsigned short* sa = A + (size_t)(bm*128 + row)*Din + kb*32 + kel;
            const unsigned short* sb = W + (size_t)(bn*128 + row)*Din + kb*32 + kel;
            __builtin_amdgcn_global_load_lds(
                (const __attribute__((address_space(1))) uint32_t*)sa,
                (__attribute__((address_space(3))) uint32_t*)((char*)As + i*4096 + wave*1024),
                16, 0, 0);
            __builtin_amdgcn_global_load_lds(
                (const __attribute__((address_space(1))) uint32_t*)sb,
                (__attribute__((address_space(3))) uint32_t*)((char*)Bs + i*4096 + wave*1024),
                16, 0, 0);
        }
        __syncthreads();
        half8 af[4], bf[4];
#pragma unroll
        for (int mt = 0; mt < 4; ++mt)
            af[mt] = *(const half8*)((const char*)As + (wm*64 + mt*16 + ln)*64 + q*16);
#pragma unroll
        for (int nt = 0; nt < 4; ++nt)
            bf[nt] = *(const half8*)((const char*)Bs + (wn*64 + nt*16 + ln)*64 + q*16);
#pragma unroll
        for (int mt = 0; mt < 4; ++mt)
#pragma unroll
            for (int nt = 0; nt < 4; ++nt)
                acc[mt][nt] = __builtin_amdgcn_mfma_f32_16x16x32_f16(af[mt], bf[nt], acc[mt][nt], 0, 0, 0);
    }
    // epilogue: transposed store. tile row = t*64 + brow with t = bm*2+wm (128 rows = 2 t).
    const int tt = bm*2 + wm;
#pragma unroll
    for (int mt = 0; mt < 4; ++mt)
#pragma unroll
        for (int nt = 0; nt < 4; ++nt) {
            int col = bn*128 + wn*64 + nt*16 + ln;
            int gate = col >> 9, colg = col & 511;
            union { unsigned short u[4]; ull v; } p;
#pragma unroll
            for (int r = 0; r < 4; ++r) p.u[r] = f2h(acc[mt][nt][r]);
            __builtin_nontemporal_store(p.v,
                (ull*)(out + (((size_t)tt*4 + gate)*512 + colg)*64 + mt*16 + q*4));
        }
}

// ---------------- recurrent kernel: one layer, both directions ----------------
// 128 WGs x 512 threads (8 waves). WG = (dir, bh batch/16, cg: 32 h-cols).
// Wave wv = gate(wv>>1) x col-half(wv&1). W_hh slice in REGISTERS (16 half8).
// h exchange: 4-slot tagged ring, 16B sc0/sc1 poll loads (load IS the poll,
// per-u16 tags), staged once into swizzled LDS; gate regroup via LDS accbuf;
// waves 0,1 do pointwise + tagged 8B-atomic ring store.
__global__ __launch_bounds__(512, 2) void rec_kernel(
    const unsigned short* __restrict__ xg,    // [dir][t][gate][hcol][brow] fp16, bias-free
    const float* __restrict__ whhf,           // [2048][512] fp32
    const float* __restrict__ whhb,
    const float* __restrict__ bias,           // [2 dir][2048] fp32 (b_ih+b_hh)
    unsigned short* __restrict__ hbuf,        // ring [4 slot][2 dir][64][512] fp16, tagged
    unsigned short* __restrict__ outh,        // layer0: in1 [T][64][1024] fp16
    float* __restrict__ outf,                 // layer1: d_out fp32 [T][64][1024]
    const int layer)
{
    __shared__ __align__(16) unsigned short h_lds[8192];   // 16KB: [16 rows][512 cols], XOR-swizzled
    __shared__ __align__(16) float accbuf[2048];           // 8KB: [wv 8][col16][row16] f32
    __shared__ __align__(16) unsigned short htile[512];    // 1KB: repack scratch, [wc][256]

    const int bx = blockIdx.x;                 // 128 WGs
    const int dir = bx & 1, bh = (bx >> 1) & 3, cg = bx >> 3;
    const int R0 = bh * 16, C0 = cg * 32;
    const int tid = threadIdx.x;
    const int wv = tid >> 6, lane = tid & 63;
    const int g = wv >> 1, wc = wv & 1;
    const int ln = lane & 15, q = lane >> 4;
    const float* whhg = dir ? whhb : whhf;

    // per-layer orthogonal tag alphabet (parity 0 / parity 1); dword patterns
    // are uniform across the 16B chunk (period = 1 dword).
    const ull pat0 = layer ? PAT_L1A : 0ULL;
    const ull pat1 = layer ? PAT_L1B : TAGMASK;
    const uint32_t ep0 = (uint32_t)(pat0 & 0xffffffffULL);
    const uint32_t ep1 = (uint32_t)(pat1 & 0xffffffffULL);

    // ---- W_hh slice -> registers: wave's gate g, cols C0+wc*16+ln, all K ----
    // b-frag for MFMA kk: lane holds W[col][kk*32 + q*8 .. +8] as half8.
    half8 wreg[16];
    {
        const int wrow = g*512 + C0 + wc*16 + ln;
        const float* wsrc = whhg + (size_t)wrow * 512 + q*8;
#pragma unroll
        for (int kk = 0; kk < 16; ++kk) {
            float4 v0 = *(const float4*)(wsrc + kk*32);
            float4 v1 = *(const float4*)(wsrc + kk*32 + 4);
            union { unsigned short u[8]; half8 v; } p;
            p.u[0]=f2h(v0.x); p.u[1]=f2h(v0.y); p.u[2]=f2h(v0.z); p.u[3]=f2h(v0.w);
            p.u[4]=f2h(v1.x); p.u[5]=f2h(v1.y); p.u[6]=f2h(v1.z); p.u[7]=f2h(v1.w);
            wreg[kk] = p.v;
        }
    }

    const unsigned short* xgd = xg + (size_t)dir * 32768 * 2048;
    const float* biasd = bias + dir * 2048;
    const int myc = C0 + wc*16 + ln;           // pointwise column (waves 0,1)
    float bv0 = biasd[0*512 + myc];
    float bv1 = biasd[1*512 + myc];
    float bv2 = biasd[2*512 + myc];
    float bv3 = biasd[3*512 + myc];
    float carr[4] = {0.f, 0.f, 0.f, 0.f};

    // cooperative h-tile load mapping: lane loads 32B = 2 x 16B chunks
    const int prow = tid >> 5;                 // 0..15 (row within bh tile)
    const int pcol = (tid & 31) * 16;          // u16 col of first chunk
    const int swz  = (prow & 7) << 4;          // XOR swizzle (16B granular)
    const int wb0 = prow*1024 + ((pcol*2)      ^ swz);
    const int wb1 = prow*1024 + ((pcol*2 + 16) ^ swz);

#pragma unroll 1
    for (int s = 0; s < 512; ++s) {
        const int t = dir ? (511 - s) : s;

        // xg prefetch (pointwise waves): 4 x 8B non-temporal loads.
        ull xv64[4] = {0,0,0,0};
        if (g == 0) {
#pragma unroll
            for (int nt_ = 0; nt_ < 4; ++nt_)
                xv64[nt_] = __builtin_nontemporal_load(
                    (const ull*)(xgd + ((size_t)(t*4 + nt_)*512 + myc)*64 + bh*16 + q*4));
        }

        // ---- poll + stage h_{s-1}: load IS the poll (per-u16 tags) ----
        if (s > 0) {
            const int slot_r = (s - 1) & 3;
            const uint32_t ep = (((s - 1) >> 2) & 1) ? ep1 : ep0;
            const uint32_t* src = (const uint32_t*)(hbuf
                + ((size_t)(slot_r*2 + dir)*64 + R0 + prow)*512 + pcol);
            u32x4 r0, r1;
            bool ok = false;
            for (int it = 0; it < (1 << 13) && !ok; ++it) {
                asm volatile(
                    "global_load_dwordx4 %0, %2, off sc0 sc1\n\t"
                    "global_load_dwordx4 %1, %3, off sc0 sc1\n\t"
                    "s_waitcnt vmcnt(0)"
                    : "=&v"(r0), "=&v"(r1)
                    : "v"(src), "v"(src + 4)
                    : "memory");
                uint32_t bad = 0;
#pragma unroll
                for (int c = 0; c < 4; ++c) bad |= (r0[c] ^ ep) & TM32;
#pragma unroll
                for (int c = 0; c < 4; ++c) bad |= (r1[c] ^ ep) & TM32;
                ok = (bad == 0);
            }
#pragma unroll
            for (int c = 0; c < 4; ++c) { r0[c] &= ~TM32; r1[c] &= ~TM32; }
            *(u32x4*)((char*)h_lds + wb0) = r0;
            *(u32x4*)((char*)h_lds + wb1) = r1;
        }
        __syncthreads();   // bar1: h_lds staged

        // ---- MFMA: 16 x (a from LDS, b from regs), one gate x 16 cols ----
        f32x4 acc = (f32x4){0.f, 0.f, 0.f, 0.f};
        if (s > 0) {
            const char* hbase = (const char*)h_lds + ln*1024;
            const int lswz = (ln & 7) << 4;
#pragma unroll
            for (int kk = 0; kk < 16; ++kk) {
                half8 a = *(const half8*)(hbase + ((kk*64 + q*16) ^ lswz));
                acc = __builtin_amdgcn_mfma_f32_16x16x32_f16(a, wreg[kk], acc, 0, 0, 0);
            }
        }
        *(f32x4*)&accbuf[(wv*16 + ln)*16 + q*4] = acc;   // [wv][col ln][rows q*4..+3]
        __syncthreads();   // bar2: accbuf ready

        // ---- pointwise + stores (waves 0,1); others fall through to next poll ----
        if (g == 0) {
            f32x4 a0 = *(const f32x4*)&accbuf[((0*2 + wc)*16 + ln)*16 + q*4];
            f32x4 a1 = *(const f32x4*)&accbuf[((1*2 + wc)*16 + ln)*16 + q*4];
            f32x4 a2 = *(const f32x4*)&accbuf[((2*2 + wc)*16 + ln)*16 + q*4];
            f32x4 a3 = *(const f32x4*)&accbuf[((3*2 + wc)*16 + ln)*16 + q*4];
            unsigned short hs[4];
#pragma unroll
            for (int r = 0; r < 4; ++r) {
                float gi = a0[r] + h2f((unsigned short)(xv64[0] >> (16*r))) + bv0;
                float gf = a1[r] + h2f((unsigned short)(xv64[1] >> (16*r))) + bv1;
                float gg = a2[r] + h2f((unsigned short)(xv64[2] >> (16*r))) + bv2;
                float go = a3[r] + h2f((unsigned short)(xv64[3] >> (16*r))) + bv3;
                float si = 1.f / (1.f + __expf(-gi));
                float sf = 1.f / (1.f + __expf(-gf));
                float so = 1.f / (1.f + __expf(-go));
                float tg = 2.f / (1.f + __expf(-2.f*gg)) - 1.f;
                float c  = sf * carr[r] + si * tg;
                carr[r] = c;
                float th = 2.f / (1.f + __expf(-2.f*c)) - 1.f;
                hs[r] = f2h(so * th);
            }
            // repack 16x16 tile via per-wave LDS scratch (intra-wave, no barrier)
            unsigned short* ht = htile + wc*256;
#pragma unroll
            for (int r = 0; r < 4; ++r) ht[(q*4 + r)*16 + ln] = hs[r];
            ull hv64 = *(const ull*)(ht + (lane >> 2)*16 + (lane & 3)*4);
            const int row  = R0 + (lane >> 2);
            const int colw = C0 + wc*16 + (lane & 3)*4;

            // ring store FIRST (critical path): tagged, single 8B relaxed atomic.
            const int slot_w = s & 3;
            const ull wpat = ((s >> 2) & 1) ? pat1 : pat0;
            AS((ull*)(hbuf + ((size_t)(slot_w*2 + dir)*64 + row)*512 + colw), hv64 | wpat);

            // layer output: plain non-temporal store, off the critical path.
            if (layer == 0) {
                __builtin_nontemporal_store(hv64,
                    (ull*)(outh + ((size_t)t*64 + row)*1024 + dir*512 + colw));
            } else {
                union { ull u; unsigned short us[4]; } pu; pu.u = hv64;
                union { ull u; float f[2]; } o0, o1;
                o0.f[0] = h2f(pu.us[0]); o0.f[1] = h2f(pu.us[1]);
                o1.f[0] = h2f(pu.us[2]); o1.f[1] = h2f(pu.us[3]);
                ull* dst = (ull*)(outf + ((size_t)t*64 + row)*1024 + dir*512 + colw);
                __builtin_nontemporal_store(o0.u, dst);
                __builtin_nontemporal_store(o1.u, dst + 1);
            }
        }
    }
}

extern "C" void kernel_launch(void* const* d_in, const int* in_sizes, int n_in,
                              void* d_out, int out_size, void* d_ws, size_t ws_size,
                              hipStream_t stream)
{
    (void)in_sizes; (void)n_in; (void)out_size; (void)ws_size;
    const float* x       = (const float*)d_in[0];
    const float* w_ih0_f = (const float*)d_in[1];
    const float* w_hh0_f = (const float*)d_in[2];
    const float* b_ih0_f = (const float*)d_in[3];
    const float* b_hh0_f = (const float*)d_in[4];
    const float* w_ih0_b = (const float*)d_in[5];
    const float* w_hh0_b = (const float*)d_in[6];
    const float* b_ih0_b = (const float*)d_in[7];
    const float* b_hh0_b = (const float*)d_in[8];
    const float* w_ih1_f = (const float*)d_in[9];
    const float* w_hh1_f = (const float*)d_in[10];
    const float* b_ih1_f = (const float*)d_in[11];
    const float* b_hh1_f = (const float*)d_in[12];
    const float* w_ih1_b = (const float*)d_in[13];
    const float* w_hh1_b = (const float*)d_in[14];
    const float* b_ih1_b = (const float*)d_in[15];
    const float* b_hh1_b = (const float*)d_in[16];

    // workspace layout (bytes): xg 256MB | wih_h 12MB | bias 32KB | hbuf ring 512KB
    char* ws = (char*)d_ws;
    unsigned short* xg    = (unsigned short*)(ws + 0);
    unsigned short* wihh  = (unsigned short*)(ws + 268435456L);
    float*          bias  = (float*)         (ws + 281018368L);
    unsigned short* hbuf  = (unsigned short*)(ws + 281051136L);

    // scratch stashed inside d_out (consumed before final output is written):
    unsigned short* in1 = (unsigned short*)d_out;                      // 67MB fp16 [T][64][1024]
    unsigned short* xh  = (unsigned short*)((char*)d_out + 67108864L); // 33.5MB fp16 x
    float* outf = (float*)d_out;

    prep_kernel<<<dim3(1024), dim3(256), 0, stream>>>(
        x, w_ih0_f, w_ih0_b, w_ih1_f, w_ih1_b,
        b_ih0_f, b_hh0_f, b_ih0_b, b_hh0_b,
        b_ih1_f, b_hh1_f, b_ih1_b, b_hh1_b,
        xh, wihh, bias, (uint32_t*)hbuf);

    // layer 0 (tag alphabet {0000,1111})
    gemm_xg<<<dim3(16, 256, 2), dim3(256), 0, stream>>>(
        xh, wihh, wihh + 1048576, xg, 512);
    rec_kernel<<<dim3(128), dim3(512), 0, stream>>>(
        xg, w_hh0_f, w_hh0_b, bias, hbuf, in1, (float*)nullptr, 0);

    // layer 1 (tag alphabet {1010,0101} — orthogonal to L0 residue and to init)
    gemm_xg<<<dim3(16, 256, 2), dim3(256), 0, stream>>>(
        in1, wihh + 2097152, wihh + 4194304, xg, 1024);
    rec_kernel<<<dim3(128), dim3(512), 0, stream>>>(
        xg, w_hh1_f, w_hh1_b, bias + 4096, hbuf,
        (unsigned short*)nullptr, outf, 1);
}

// Round 6
// 5106.157 us; speedup vs baseline: 1.4846x; 1.0946x over previous
//
#include <hip/hip_runtime.h>
#include <hip/hip_bf16.h>
#include <stdint.h>

// LSTM bidirectional 2-layer, T=512 B=64 D=H=512.
// prep(cast+bias+ring-init) -> gemm_xg(L0) -> rec(L0) -> gemm_xg(L1) -> rec(L1).
// R7: single-hop sync on a COMPACT 512KB ring with per-u16 tag-in-data
//   (h in [-1,1] => fp16 bit14 always 0). Orthogonal per-layer tag alphabets:
//   L0 {0000,1111}, L1 {1010,0101}, ring init = neutral 0011 (matches nothing).
// R8: fat WGs, W_hh in registers, 16B sc0/sc1 poll loads (load IS the poll).
// R9: DUAL-CHAIN interleave. R8 counters: per-step 4.7us vs ~0.5us compute ->
//   the serialized chain (poll-observe -> MFMA -> pointwise -> store-visible)
//   is the limiter, not request count. fwd and bwd recurrences are independent:
//   one WG now owns BOTH dirs for its (bh, 32-col group) and alternates
//   A(fwd)/B(bwd) phases, hiding each chain's L3 latency under the other's
//   compute. 64 WGs x 512 thr. Also: conflict-free staging chunk map
//   (lane-consecutive 16B), accbuf padded stride-20 (was 8-way conflicted),
//   xg prefetch one iteration ahead.
// R5 carry-over: xg stores/loads non-temporal (268MB read-once stream).

typedef __attribute__((ext_vector_type(8))) _Float16 half8;
typedef __attribute__((ext_vector_type(4))) float f32x4;
typedef __attribute__((ext_vector_type(4))) uint32_t u32x4;
typedef unsigned long long ull;

#define AS(p, v) __hip_atomic_store((p), (v), __ATOMIC_RELAXED, __HIP_MEMORY_SCOPE_AGENT)

#define TAGMASK 0x4000400040004000ULL   // bit14 of halves 0..3
#define TM32    0x40004000u
#define PAT_L1A 0x0000400000004000ULL   // halves 0,2  (L1 parity 0)
#define PAT_L1B 0x4000000040000000ULL   // halves 1,3  (L1 parity 1)
// neutral ring-init pattern: halves 0,1 tagged -> matches no layer expectation
#define PAT_INIT_LO 0x40004000u
#define PAT_INIT_HI 0x00000000u

__device__ __forceinline__ unsigned short f2h(float f) {
    union { _Float16 h; unsigned short u; } c; c.h = (_Float16)f; return c.u;
}
__device__ __forceinline__ float h2f(unsigned short u) {
    union { _Float16 h; unsigned short u; } c; c.u = u; return (float)c.h;
}

// ---------------- prep: casts, bias sums, ring init (neutral pattern) ----------------
__global__ __launch_bounds__(256) void prep_kernel(
    const float* __restrict__ x,
    const float* __restrict__ w0f, const float* __restrict__ w0b,
    const float* __restrict__ w1f, const float* __restrict__ w1b,
    const float* __restrict__ bi0f, const float* __restrict__ bh0f,
    const float* __restrict__ bi0b, const float* __restrict__ bh0b,
    const float* __restrict__ bi1f, const float* __restrict__ bh1f,
    const float* __restrict__ bi1b, const float* __restrict__ bh1b,
    unsigned short* __restrict__ xh,
    unsigned short* __restrict__ wihh,
    float* __restrict__ bias,
    uint32_t* __restrict__ hbufi)          // ring init: 512KB neutral pattern
{
    const long total = 5801984L;   // units of 16B quads
    long stride = (long)gridDim.x * blockDim.x;
    for (long i = (long)blockIdx.x * blockDim.x + threadIdx.x; i < total; i += stride) {
        if (i < 4194304L) {                       // x: fp32 -> fp16 (16.78M elems)
            float4 v = ((const float4*)x)[i];
            ushort4 o; o.x=f2h(v.x); o.y=f2h(v.y); o.z=f2h(v.z); o.w=f2h(v.w);
            ((ushort4*)xh)[i] = o;
        } else if (i < 5767168L) {                // w_ih casts: [w0f][w0b][w1f][w1b]
            long j = i - 4194304L;
            const float* src; long sq;
            if (j < 262144L)       { src = w0f; sq = j;            }
            else if (j < 524288L)  { src = w0b; sq = j - 262144L;  }
            else if (j < 1048576L) { src = w1f; sq = j - 524288L;  }
            else                   { src = w1b; sq = j - 1048576L; }
            float4 v = ((const float4*)src)[sq];
            ushort4 o; o.x=f2h(v.x); o.y=f2h(v.y); o.z=f2h(v.z); o.w=f2h(v.w);
            ((ushort4*)wihh)[j] = o;
        } else if (i < 5769216L) {                // bias sums: b_ih + b_hh, 4 x 2048 fp32
            long j = i - 5767168L;                // 0..2047 quads
            int ld = (int)(j >> 9);
            long cq = j & 511L;
            const float* bi = ld==0?bi0f: ld==1?bi0b: ld==2?bi1f:bi1b;
            const float* bh = ld==0?bh0f: ld==1?bh0b: ld==2?bh1f:bh1b;
            float4 a = ((const float4*)bi)[cq];
            float4 b = ((const float4*)bh)[cq];
            float4 o; o.x=a.x+b.x; o.y=a.y+b.y; o.z=a.z+b.z; o.w=a.w+b.w;
            ((float4*)bias)[ld*512 + cq] = o;
        } else {                                  // ring init: 32768 quads = 512KB
            long j = i - 5769216L;
            uint4 p; p.x=PAT_INIT_LO; p.y=PAT_INIT_HI; p.z=PAT_INIT_LO; p.w=PAT_INIT_HI;
            ((uint4*)hbufi)[j] = p;
        }
    }
}

// ---------------- xg GEMM: xg = A @ W^T, fp16 out, TRANSPOSED layout ----------------
__global__ __launch_bounds__(256) void gemm_xg(
    const unsigned short* __restrict__ A,
    const unsigned short* __restrict__ Wf,
    const unsigned short* __restrict__ Wb,
    unsigned short* __restrict__ xg,
    int Din)
{
    __shared__ __align__(16) unsigned short As[4096];   // 128 rows x 32 k, fp16
    __shared__ __align__(16) unsigned short Bs[4096];
    const int dir = blockIdx.z;
    const unsigned short* W = dir ? Wb : Wf;
    unsigned short* out = xg + (size_t)dir * 32768 * 2048;
    const int bn = blockIdx.x, bm = blockIdx.y;
    const int tid = threadIdx.x;
    const int wave = tid >> 6, lane = tid & 63;
    const int q = lane >> 4, ln = lane & 15;
    const int wm = wave >> 1, wn = wave & 1;

    f32x4 acc[4][4];
#pragma unroll
    for (int a = 0; a < 4; ++a)
#pragma unroll
        for (int b = 0; b < 4; ++b) acc[a][b] = (f32x4){0.f, 0.f, 0.f, 0.f};

    const int kiter = Din >> 5;
    for (int kb = 0; kb < kiter; ++kb) {
        __syncthreads();
#pragma unroll
        for (int i = 0; i < 2; ++i) {
            int off = i*4096 + wave*1024 + lane*16;   // byte offset in 8KB tile
            int row = off >> 6;
            int kel = (off & 63) >> 1;
            const unsigned short* sa = A + (size_t)(bm*128 + row)*Din + kb*32 + kel;
            const unsigned short* sb = W + (size_t)(bn*128 + row)*Din + kb*32 + kel;
            __builtin_amdgcn_global_load_lds(
                (const __attribute__((address_space(1))) uint32_t*)sa,
                (__attribute__((address_space(3))) uint32_t*)((char*)As + i*4096 + wave*1024),
                16, 0, 0);
            __builtin_amdgcn_global_load_lds(
                (const __attribute__((address_space(1))) uint32_t*)sb,
                (__attribute__((address_space(3))) uint32_t*)((char*)Bs + i*4096 + wave*1024),
                16, 0, 0);
        }
        __syncthreads();
        half8 af[4], bf[4];
#pragma unroll
        for (int mt = 0; mt < 4; ++mt)
            af[mt] = *(const half8*)((const char*)As + (wm*64 + mt*16 + ln)*64 + q*16);
#pragma unroll
        for (int nt = 0; nt < 4; ++nt)
            bf[nt] = *(const half8*)((const char*)Bs + (wn*64 + nt*16 + ln)*64 + q*16);
#pragma unroll
        for (int mt = 0; mt < 4; ++mt)
#pragma unroll
            for (int nt = 0; nt < 4; ++nt)
                acc[mt][nt] = __builtin_amdgcn_mfma_f32_16x16x32_f16(af[mt], bf[nt], acc[mt][nt], 0, 0, 0);
    }
    const int tt = bm*2 + wm;
#pragma unroll
    for (int mt = 0; mt < 4; ++mt)
#pragma unroll
        for (int nt = 0; nt < 4; ++nt) {
            int col = bn*128 + wn*64 + nt*16 + ln;
            int gate = col >> 9, colg = col & 511;
            union { unsigned short u[4]; ull v; } p;
#pragma unroll
            for (int r = 0; r < 4; ++r) p.u[r] = f2h(acc[mt][nt][r]);
            __builtin_nontemporal_store(p.v,
                (ull*)(out + (((size_t)tt*4 + gate)*512 + colg)*64 + mt*16 + q*4));
        }
}

// ---------------- recurrent kernel: one layer, BOTH directions per WG ----------------
// 64 WGs x 512 threads (8 waves). WG = (bh batch/16, cg: 32 h-cols), both dirs.
// Chain A = fwd (dir 0), chain B = bwd (dir 1), phases interleaved so each
// chain's L3 poll latency hides under the other chain's MFMA+pointwise.
struct RecCtx {
    const unsigned short* hbuf_c;
    unsigned short* hbuf;
    unsigned short* outh;
    float* outf;
    int layer, R0, C0, tid, wv, lane, g, wc, ln, q;
    int c0row, colq, wb0, wb1;
    uint32_t ep0, ep1;
    ull pat0, pat1;
};

__device__ __forceinline__ void poll_stage(const RecCtx& cx, int d, int sm1,
                                           unsigned short* lbuf)
{
    const int slot_r = sm1 & 3;
    const uint32_t ep = ((sm1 >> 2) & 1) ? cx.ep1 : cx.ep0;
    const uint32_t* s0 = (const uint32_t*)(cx.hbuf_c
        + ((size_t)(slot_r*2 + d)*64 + cx.R0 + cx.c0row)*512 + cx.colq);
    const uint32_t* s1 = (const uint32_t*)(cx.hbuf_c
        + ((size_t)(slot_r*2 + d)*64 + cx.R0 + cx.c0row + 8)*512 + cx.colq);
    u32x4 r0, r1;
    bool ok = false;
    for (int it = 0; it < (1 << 13) && !ok; ++it) {
        asm volatile(
            "global_load_dwordx4 %0, %2, off sc0 sc1\n\t"
            "global_load_dwordx4 %1, %3, off sc0 sc1\n\t"
            "s_waitcnt vmcnt(0)"
            : "=&v"(r0), "=&v"(r1)
            : "v"(s0), "v"(s1)
            : "memory");
        uint32_t bad = 0;
#pragma unroll
        for (int c = 0; c < 4; ++c) bad |= (r0[c] ^ ep) & TM32;
#pragma unroll
        for (int c = 0; c < 4; ++c) bad |= (r1[c] ^ ep) & TM32;
        ok = (bad == 0);
    }
#pragma unroll
    for (int c = 0; c < 4; ++c) { r0[c] &= ~TM32; r1[c] &= ~TM32; }
    *(u32x4*)((char*)lbuf + cx.wb0) = r0;
    *(u32x4*)((char*)lbuf + cx.wb1) = r1;
}

__device__ __forceinline__ void mfma_phase(const RecCtx& cx,
    const unsigned short* lbuf, const half8* wreg, float* achb)
{
    f32x4 acc = (f32x4){0.f, 0.f, 0.f, 0.f};
    const char* hbase = (const char*)lbuf + cx.ln*1024;
    const int lswz = (cx.ln & 7) << 4;
#pragma unroll
    for (int kk = 0; kk < 16; ++kk) {
        half8 a = *(const half8*)(hbase + ((kk*64 + cx.q*16) ^ lswz));
        acc = __builtin_amdgcn_mfma_f32_16x16x32_f16(a, wreg[kk], acc, 0, 0, 0);
    }
    *(f32x4*)&achb[(cx.wv*16 + cx.ln)*20 + cx.q*4] = acc;
}

__device__ __forceinline__ void pointwise(const RecCtx& cx, int d, int s, int t,
    const ull* xv, float* carr, const float* achb, unsigned short* htb,
    float bv0, float bv1, float bv2, float bv3)
{
    f32x4 a0 = *(const f32x4*)&achb[((0*2 + cx.wc)*16 + cx.ln)*20 + cx.q*4];
    f32x4 a1 = *(const f32x4*)&achb[((1*2 + cx.wc)*16 + cx.ln)*20 + cx.q*4];
    f32x4 a2 = *(const f32x4*)&achb[((2*2 + cx.wc)*16 + cx.ln)*20 + cx.q*4];
    f32x4 a3 = *(const f32x4*)&achb[((3*2 + cx.wc)*16 + cx.ln)*20 + cx.q*4];
    unsigned short hs[4];
#pragma unroll
    for (int r = 0; r < 4; ++r) {
        float gi = a0[r] + h2f((unsigned short)(xv[0] >> (16*r))) + bv0;
        float gf = a1[r] + h2f((unsigned short)(xv[1] >> (16*r))) + bv1;
        float gg = a2[r] + h2f((unsigned short)(xv[2] >> (16*r))) + bv2;
        float go = a3[r] + h2f((unsigned short)(xv[3] >> (16*r))) + bv3;
        float si = 1.f / (1.f + __expf(-gi));
        float sf = 1.f / (1.f + __expf(-gf));
        float so = 1.f / (1.f + __expf(-go));
        float tg = 2.f / (1.f + __expf(-2.f*gg)) - 1.f;
        float c  = sf * carr[r] + si * tg;
        carr[r] = c;
        float th = 2.f / (1.f + __expf(-2.f*c)) - 1.f;
        hs[r] = f2h(so * th);
    }
    // repack 16x16 tile via per-wave LDS scratch (intra-wave, no barrier)
    unsigned short* ht = htb + cx.wc*256;
#pragma unroll
    for (int r = 0; r < 4; ++r) ht[(cx.q*4 + r)*16 + cx.ln] = hs[r];
    ull hv64 = *(const ull*)(ht + (cx.lane >> 2)*16 + (cx.lane & 3)*4);
    const int row  = cx.R0 + (cx.lane >> 2);
    const int colw = cx.C0 + cx.wc*16 + (cx.lane & 3)*4;

    // ring store FIRST (critical path): tagged, single 8B relaxed atomic.
    const int slot_w = s & 3;
    const ull wpat = ((s >> 2) & 1) ? cx.pat1 : cx.pat0;
    AS((ull*)(cx.hbuf + ((size_t)(slot_w*2 + d)*64 + row)*512 + colw), hv64 | wpat);

    // layer output: plain non-temporal store, off the critical path.
    if (cx.layer == 0) {
        __builtin_nontemporal_store(hv64,
            (ull*)(cx.outh + ((size_t)t*64 + row)*1024 + d*512 + colw));
    } else {
        union { ull u; unsigned short us[4]; } pu; pu.u = hv64;
        union { ull u; float f[2]; } o0, o1;
        o0.f[0] = h2f(pu.us[0]); o0.f[1] = h2f(pu.us[1]);
        o1.f[0] = h2f(pu.us[2]); o1.f[1] = h2f(pu.us[3]);
        ull* dst = (ull*)(cx.outf + ((size_t)t*64 + row)*1024 + d*512 + colw);
        __builtin_nontemporal_store(o0.u, dst);
        __builtin_nontemporal_store(o1.u, dst + 1);
    }
}

__global__ __launch_bounds__(512, 2) void rec_kernel(
    const unsigned short* __restrict__ xg,    // [dir][t][gate][hcol][brow] fp16, bias-free
    const float* __restrict__ whhf,           // [2048][512] fp32
    const float* __restrict__ whhb,
    const float* __restrict__ bias,           // [2 dir][2048] fp32 (b_ih+b_hh)
    unsigned short* __restrict__ hbuf,        // ring [4 slot][2 dir][64][512] fp16, tagged
    unsigned short* __restrict__ outh,        // layer0: in1 [T][64][1024] fp16
    float* __restrict__ outf,                 // layer1: d_out fp32 [T][64][1024]
    const int layer)
{
    __shared__ __align__(16) unsigned short h_lds[2][8192];   // 32KB: [chain][16r][512c] swz
    __shared__ __align__(16) float accbuf[2][2560];           // 20KB: [chain][wv*16+ln][20] pad
    __shared__ __align__(16) unsigned short htile[2][512];    // 2KB repack scratch

    const int bx = blockIdx.x;                 // 64 WGs
    RecCtx cx;
    cx.hbuf_c = hbuf; cx.hbuf = hbuf; cx.outh = outh; cx.outf = outf;
    cx.layer = layer;
    const int bh = bx & 3, cg = bx >> 2;
    cx.R0 = bh * 16; cx.C0 = cg * 32;
    cx.tid = threadIdx.x;
    cx.wv = cx.tid >> 6; cx.lane = cx.tid & 63;
    cx.g = cx.wv >> 1; cx.wc = cx.wv & 1;
    cx.ln = cx.lane & 15; cx.q = cx.lane >> 4;
    cx.pat0 = layer ? PAT_L1A : 0ULL;
    cx.pat1 = layer ? PAT_L1B : TAGMASK;
    cx.ep0 = (uint32_t)(cx.pat0 & 0xffffffffULL);
    cx.ep1 = (uint32_t)(cx.pat1 & 0xffffffffULL);
    // conflict-free staging map: thread owns chunks tid and tid+512 (16B each)
    cx.c0row = cx.tid >> 6;                    // rows 0..7 (+8 for second chunk)
    cx.colq  = (cx.tid & 63) * 8;              // u16 col of chunk
    cx.wb0 = cx.c0row*1024 + (((cx.tid & 63)*16) ^ ((cx.c0row & 7) << 4));
    cx.wb1 = (cx.c0row + 8)*1024 + (((cx.tid & 63)*16) ^ ((cx.c0row & 7) << 4));

    // ---- W_hh -> registers, BOTH dirs (static names; rule #20) ----
    half8 wregA[16], wregB[16];
    {
        const int wrow = cx.g*512 + cx.C0 + cx.wc*16 + cx.ln;
        const float* srcA = whhf + (size_t)wrow * 512 + cx.q*8;
        const float* srcB = whhb + (size_t)wrow * 512 + cx.q*8;
#pragma unroll
        for (int kk = 0; kk < 16; ++kk) {
            float4 v0 = *(const float4*)(srcA + kk*32);
            float4 v1 = *(const float4*)(srcA + kk*32 + 4);
            union { unsigned short u[8]; half8 v; } p;
            p.u[0]=f2h(v0.x); p.u[1]=f2h(v0.y); p.u[2]=f2h(v0.z); p.u[3]=f2h(v0.w);
            p.u[4]=f2h(v1.x); p.u[5]=f2h(v1.y); p.u[6]=f2h(v1.z); p.u[7]=f2h(v1.w);
            wregA[kk] = p.v;
        }
#pragma unroll
        for (int kk = 0; kk < 16; ++kk) {
            float4 v0 = *(const float4*)(srcB + kk*32);
            float4 v1 = *(const float4*)(srcB + kk*32 + 4);
            union { unsigned short u[8]; half8 v; } p;
            p.u[0]=f2h(v0.x); p.u[1]=f2h(v0.y); p.u[2]=f2h(v0.z); p.u[3]=f2h(v0.w);
            p.u[4]=f2h(v1.x); p.u[5]=f2h(v1.y); p.u[6]=f2h(v1.z); p.u[7]=f2h(v1.w);
            wregB[kk] = p.v;
        }
    }

    const unsigned short* xgdA = xg;
    const unsigned short* xgdB = xg + (size_t)32768 * 2048;
    const int myc = cx.C0 + cx.wc*16 + cx.ln;
    float bvA0 = bias[0*512 + myc],        bvA1 = bias[1*512 + myc];
    float bvA2 = bias[2*512 + myc],        bvA3 = bias[3*512 + myc];
    float bvB0 = bias[2048 + 0*512 + myc], bvB1 = bias[2048 + 1*512 + myc];
    float bvB2 = bias[2048 + 2*512 + myc], bvB3 = bias[2048 + 3*512 + myc];
    float carrA[4] = {0.f,0.f,0.f,0.f}, carrB[4] = {0.f,0.f,0.f,0.f};
    ull xvA[4] = {0,0,0,0}, xvB[4] = {0,0,0,0};
    ull xvAn[4] = {0,0,0,0}, xvBn[4] = {0,0,0,0};

    const size_t xoff = (size_t)bh*16 + cx.q*4;   // brow base within xg row

    // ---- prologue: s=0 both chains (acc = 0) ----
    {
        // zero accbufs so pointwise reads 0
        f32x4 z = (f32x4){0.f,0.f,0.f,0.f};
        *(f32x4*)&accbuf[0][(cx.wv*16 + cx.ln)*20 + cx.q*4] = z;
        *(f32x4*)&accbuf[1][(cx.wv*16 + cx.ln)*20 + cx.q*4] = z;
        __syncthreads();
        if (cx.g == 0) {
#pragma unroll
            for (int k = 0; k < 4; ++k) {
                xvA[k] = __builtin_nontemporal_load(
                    (const ull*)(xgdA + ((size_t)(0*4 + k)*512 + myc)*64 + xoff));
                xvB[k] = __builtin_nontemporal_load(
                    (const ull*)(xgdB + ((size_t)(511*4 + k)*512 + myc)*64 + xoff));
            }
            pointwise(cx, 0, 0, 0,   xvA, carrA, accbuf[0], htile[0], bvA0,bvA1,bvA2,bvA3);
            pointwise(cx, 1, 0, 511, xvB, carrB, accbuf[1], htile[1], bvB0,bvB1,bvB2,bvB3);
#pragma unroll
            for (int k = 0; k < 4; ++k) {
                xvA[k] = __builtin_nontemporal_load(
                    (const ull*)(xgdA + ((size_t)(1*4 + k)*512 + myc)*64 + xoff));
                xvB[k] = __builtin_nontemporal_load(
                    (const ull*)(xgdB + ((size_t)(510*4 + k)*512 + myc)*64 + xoff));
            }
        }
    }

    // ---- main loop: one fwd step + one bwd step per iteration ----
#pragma unroll 1
    for (int s = 1; s < 512; ++s) {
        const int tA = s, tB = 511 - s;

        // chain A: poll h_{s-1}, stage, compute
        poll_stage(cx, 0, s - 1, h_lds[0]);
        __syncthreads();                                     // bar1
        if (cx.g == 0 && s < 511) {                          // prefetch xg for s+1
#pragma unroll
            for (int k = 0; k < 4; ++k) {
                xvAn[k] = __builtin_nontemporal_load(
                    (const ull*)(xgdA + ((size_t)((s+1)*4 + k)*512 + myc)*64 + xoff));
                xvBn[k] = __builtin_nontemporal_load(
                    (const ull*)(xgdB + ((size_t)((510-s)*4 + k)*512 + myc)*64 + xoff));
            }
        }
        mfma_phase(cx, h_lds[0], wregA, accbuf[0]);
        __syncthreads();                                     // bar2
        if (cx.g == 0)
            pointwise(cx, 0, s, tA, xvA, carrA, accbuf[0], htile[0], bvA0,bvA1,bvA2,bvA3);

        // chain B: poll h_{s-1}, stage, compute (hides A's store->visibility)
        poll_stage(cx, 1, s - 1, h_lds[1]);
        __syncthreads();                                     // bar3
        mfma_phase(cx, h_lds[1], wregB, accbuf[1]);
        __syncthreads();                                     // bar4
        if (cx.g == 0) {
            pointwise(cx, 1, s, tB, xvB, carrB, accbuf[1], htile[1], bvB0,bvB1,bvB2,bvB3);
#pragma unroll
            for (int k = 0; k < 4; ++k) { xvA[k] = xvAn[k]; xvB[k] = xvBn[k]; }
        }
    }
}

extern "C" void kernel_launch(void* const* d_in, const int* in_sizes, int n_in,
                              void* d_out, int out_size, void* d_ws, size_t ws_size,
                              hipStream_t stream)
{
    (void)in_sizes; (void)n_in; (void)out_size; (void)ws_size;
    const float* x       = (const float*)d_in[0];
    const float* w_ih0_f = (const float*)d_in[1];
    const float* w_hh0_f = (const float*)d_in[2];
    const float* b_ih0_f = (const float*)d_in[3];
    const float* b_hh0_f = (const float*)d_in[4];
    const float* w_ih0_b = (const float*)d_in[5];
    const float* w_hh0_b = (const float*)d_in[6];
    const float* b_ih0_b = (const float*)d_in[7];
    const float* b_hh0_b = (const float*)d_in[8];
    const float* w_ih1_f = (const float*)d_in[9];
    const float* w_hh1_f = (const float*)d_in[10];
    const float* b_ih1_f = (const float*)d_in[11];
    const float* b_hh1_f = (const float*)d_in[12];
    const float* w_ih1_b = (const float*)d_in[13];
    const float* w_hh1_b = (const float*)d_in[14];
    const float* b_ih1_b = (const float*)d_in[15];
    const float* b_hh1_b = (const float*)d_in[16];

    // workspace layout (bytes): xg 256MB | wih_h 12MB | bias 32KB | hbuf ring 512KB
    char* ws = (char*)d_ws;
    unsigned short* xg    = (unsigned short*)(ws + 0);
    unsigned short* wihh  = (unsigned short*)(ws + 268435456L);
    float*          bias  = (float*)         (ws + 281018368L);
    unsigned short* hbuf  = (unsigned short*)(ws + 281051136L);

    // scratch stashed inside d_out (consumed before final output is written):
    unsigned short* in1 = (unsigned short*)d_out;                      // 67MB fp16 [T][64][1024]
    unsigned short* xh  = (unsigned short*)((char*)d_out + 67108864L); // 33.5MB fp16 x
    float* outf = (float*)d_out;

    prep_kernel<<<dim3(1024), dim3(256), 0, stream>>>(
        x, w_ih0_f, w_ih0_b, w_ih1_f, w_ih1_b,
        b_ih0_f, b_hh0_f, b_ih0_b, b_hh0_b,
        b_ih1_f, b_hh1_f, b_ih1_b, b_hh1_b,
        xh, wihh, bias, (uint32_t*)hbuf);

    // layer 0 (tag alphabet {0000,1111})
    gemm_xg<<<dim3(16, 256, 2), dim3(256), 0, stream>>>(
        xh, wihh, wihh + 1048576, xg, 512);
    rec_kernel<<<dim3(64), dim3(512), 0, stream>>>(
        xg, w_hh0_f, w_hh0_b, bias, hbuf, in1, (float*)nullptr, 0);

    // layer 1 (tag alphabet {1010,0101} — orthogonal to L0 residue and to init)
    gemm_xg<<<dim3(16, 256, 2), dim3(256), 0, stream>>>(
        in1, wihh + 2097152, wihh + 4194304, xg, 1024);
    rec_kernel<<<dim3(64), dim3(512), 0, stream>>>(
        xg, w_hh1_f, w_hh1_b, bias + 4096, hbuf,
        (unsigned short*)nullptr, outf, 1);
}